// Round 1
// baseline (789.789 us; speedup 1.0000x reference)
//
#include <hip/hip_runtime.h>
#include <math.h>

// ---------------- geometry ----------------
// x: [img][3][160][60], img 0..127 (0..63 = x1, 64..127 = x2)
// conv1 5x5 VALID -> [20][156][56], relu, pool2 -> [20][78][28]
// conv2 5x5 VALID -> [25][74][24], relu, pool2 -> f [25][37][12]
// stats: mu, inv = 1/(std+0.01) per (img,c,i,j) over zero-padded 5x5 patch
// ncc[b,c,d,k,i,j] = (dot - 25 muX muY) * invX * invY / 25 ; relu; 1x1 conv w_red1 -> [64][25][37][12]
// red2 3x3 VALID -> [35][10], pool2 -> [17][5]; flatten 2125; lin1 2125->500; lin2 500->2

// ws offsets in floats
static const long OFF_C1   = 0;          // [128][20][78][28] = 5,591,040
static const long OFF_F    = 5591040;    // [128][25][444]    = 1,420,800
static const long OFF_MU   = 7011840;    // [128][25][444]
static const long OFF_IV   = 8432640;    // [128][25][444]
static const long OFF_WLT  = 9853440;    // [2125][500]       = 1,062,500
static const long OFF_PART = 0;          // overlay c1: [64][5][25][444] = 3,552,000
static const long OFF_RED1 = 3552000;    // [64][25][444] = 710,400
static const long OFF_R2P  = 4262400;    // [64][2125]    = 136,000
// total ws use: 10,915,940 floats = 43.7 MB

// ---------------- w_lin1 transpose: wlt[t][o] = wl1[o][t] ----------------
__global__ void k_wt(const float* __restrict__ wl1, float* __restrict__ wlt) {
  long idx = (long)blockIdx.x * 256 + threadIdx.x;
  if (idx < 2125L * 500) {
    long t = idx / 500, o = idx % 500;
    wlt[idx] = wl1[o * 2125 + t];
  }
}

// ---------------- conv1 + relu + pool ----------------
__global__ __launch_bounds__(256) void k_conv1(
    const float* __restrict__ x1, const float* __restrict__ x2,
    const float* __restrict__ w, const float* __restrict__ bias,
    float* __restrict__ out) {
  int img = blockIdx.x;
  int oc  = blockIdx.y;
  const float* x = (img < 64) ? (x1 + (long)img * 3 * 160 * 60)
                              : (x2 + (long)(img - 64) * 3 * 160 * 60);
  float* o = out + ((long)img * 20 + oc) * 78 * 28;
  const float* wp = w + oc * 75;
  float bv = bias[oc];
  for (int px = threadIdx.x; px < 78 * 28; px += blockDim.x) {
    int pi = px / 28, pj = px % 28;
    int ci0 = 2 * pi, cj0 = 2 * pj;
    float a00 = 0, a01 = 0, a10 = 0, a11 = 0;
    for (int ic = 0; ic < 3; ++ic) {
      const float* xp = x + (long)ic * 160 * 60 + ci0 * 60 + cj0;
      float win[6][6];
#pragma unroll
      for (int u = 0; u < 6; ++u)
#pragma unroll
        for (int v = 0; v < 6; ++v) win[u][v] = xp[u * 60 + v];
      const float* wq = wp + ic * 25;
#pragma unroll
      for (int u = 0; u < 5; ++u)
#pragma unroll
        for (int v = 0; v < 5; ++v) {
          float wv = wq[u * 5 + v];
          a00 += wv * win[u][v];
          a01 += wv * win[u][v + 1];
          a10 += wv * win[u + 1][v];
          a11 += wv * win[u + 1][v + 1];
        }
    }
    float mx = fmaxf(fmaxf(a00, a01), fmaxf(a10, a11));
    o[px] = fmaxf(mx + bv, 0.f);
  }
}

// ---------------- conv2 + relu + pool ----------------
__global__ __launch_bounds__(256) void k_conv2(
    const float* __restrict__ in, const float* __restrict__ w,
    const float* __restrict__ bias, float* __restrict__ out) {
  int img = blockIdx.x;
  int oc  = blockIdx.y;
  const float* x = in + (long)img * 20 * 78 * 28;
  float* o = out + ((long)img * 25 + oc) * 444;
  const float* wp = w + oc * 20 * 25;
  float bv = bias[oc];
  for (int px = threadIdx.x; px < 444; px += blockDim.x) {
    int pi = px / 12, pj = px % 12;
    int ci0 = 2 * pi, cj0 = 2 * pj;
    float a00 = 0, a01 = 0, a10 = 0, a11 = 0;
    for (int ic = 0; ic < 20; ++ic) {
      const float* xp = x + (long)ic * 78 * 28 + ci0 * 28 + cj0;
      float win[6][6];
#pragma unroll
      for (int u = 0; u < 6; ++u)
#pragma unroll
        for (int v = 0; v < 6; ++v) win[u][v] = xp[u * 28 + v];
      const float* wq = wp + ic * 25;
#pragma unroll
      for (int u = 0; u < 5; ++u)
#pragma unroll
        for (int v = 0; v < 5; ++v) {
          float wv = wq[u * 5 + v];
          a00 += wv * win[u][v];
          a01 += wv * win[u][v + 1];
          a10 += wv * win[u + 1][v];
          a11 += wv * win[u + 1][v + 1];
        }
    }
    float mx = fmaxf(fmaxf(a00, a01), fmaxf(a10, a11));
    o[px] = fmaxf(mx + bv, 0.f);
  }
}

// ---------------- patch stats: mu, 1/(std+eps) ----------------
__global__ __launch_bounds__(448) void k_stats(
    const float* __restrict__ f, float* __restrict__ mu, float* __restrict__ iv) {
  int img = blockIdx.x, c = blockIdx.y;
  int t = threadIdx.x;
  if (t >= 444) return;
  int i = t / 12, j = t % 12;
  const float* fp = f + ((long)img * 25 + c) * 444;
  float s = 0.f, sq = 0.f;
#pragma unroll
  for (int u = 0; u < 5; ++u) {
    int gi = i + u - 2;
    if (gi < 0 || gi >= 37) continue;
#pragma unroll
    for (int v = 0; v < 5; ++v) {
      int gj = j + v - 2;
      if (gj < 0 || gj >= 12) continue;
      float vv = fp[gi * 12 + gj];
      s += vv;
      sq += vv * vv;
    }
  }
  float m = s * 0.04f;
  float var = sq * 0.04f - m * m;
  float sd = sqrtf(fmaxf(var, 0.f));
  long idx = ((long)img * 25 + c) * 444 + t;
  mu[idx] = m;
  iv[idx] = 1.f / (sd + 0.01f);
}

// ---------------- fused NCC + relu + red1 (partial over c-groups) ----------------
__global__ __launch_bounds__(128) void k_ncc(
    const float* __restrict__ f, const float* __restrict__ mu,
    const float* __restrict__ iv, const float* __restrict__ wr1,
    float* __restrict__ part) {
  int b  = blockIdx.x;          // 0..63
  int g  = blockIdx.y;          // 0..3 -> rows i0..i0+ROWS-1
  int cz = blockIdx.z;          // 0..4 -> channels cz*5..cz*5+4
  int i0 = g * 10;
  int ROWS = min(10, 37 - i0);
  int tid = threadIdx.x;
  int j = tid % 12, r = tid / 12;
  bool active = (r < ROWS);

  __shared__ float Xt[14][16], Yt[18][16];
  __shared__ float mX[10][12], iX[10][12], mY[14][12], iY[14][12];

  const float* Xf = f + (long)b * 25 * 444;
  const float* Yf = f + (long)(64 + b) * 25 * 444;
  const float* muX_g = mu + (long)b * 25 * 444;
  const float* ivX_g = iv + (long)b * 25 * 444;
  const float* muY_g = mu + (long)(64 + b) * 25 * 444;
  const float* ivY_g = iv + (long)(64 + b) * 25 * 444;

  float acc[25];
#pragma unroll
  for (int o = 0; o < 25; ++o) acc[o] = 0.f;

  for (int cc = 0; cc < 5; ++cc) {
    int c = cz * 5 + cc;
    __syncthreads();
    for (int idx = tid; idx < 14 * 16; idx += 128) {
      int rr = idx >> 4, cl = idx & 15;
      int gi = i0 - 2 + rr, gj = cl - 2;
      Xt[rr][cl] = (gi >= 0 && gi < 37 && gj >= 0 && gj < 12)
                       ? Xf[c * 444 + gi * 12 + gj] : 0.f;
    }
    for (int idx = tid; idx < 18 * 16; idx += 128) {
      int rr = idx >> 4, cl = idx & 15;
      int gi = i0 - 4 + rr, gj = cl - 2;
      Yt[rr][cl] = (gi >= 0 && gi < 37 && gj >= 0 && gj < 12)
                       ? Yf[c * 444 + gi * 12 + gj] : 0.f;
    }
    for (int idx = tid; idx < 120; idx += 128) {
      int rr = idx / 12, gj = idx % 12;
      int gi = i0 + rr;
      bool ok = gi < 37;
      mX[rr][gj] = ok ? muX_g[c * 444 + gi * 12 + gj] : 0.f;
      iX[rr][gj] = ok ? ivX_g[c * 444 + gi * 12 + gj] : 0.f;
    }
    for (int idx = tid; idx < 168; idx += 128) {
      int rr = idx / 12, gj = idx % 12;
      int gi = i0 - 2 + rr;
      bool ok = (gi >= 0 && gi < 37);
      mY[rr][gj] = ok ? muY_g[c * 444 + gi * 12 + gj] : 0.f;
      iY[rr][gj] = ok ? ivY_g[c * 444 + gi * 12 + gj] : 0.f;
    }
    __syncthreads();

    if (active) {
      float xp[5][5];
#pragma unroll
      for (int u = 0; u < 5; ++u)
#pragma unroll
        for (int v = 0; v < 5; ++v) xp[u][v] = Xt[r + u][j + v];
      float muXv = mX[r][j], ivXv = iX[r][j];
      const float* wbase = wr1 + c * 60;
      for (int d = 0; d < 5; ++d) {
        int yi = i0 + r + d - 2;
        if (yi < 0 || yi >= 37) continue;
        float win[5][5];
#pragma unroll
        for (int u = 0; u < 5; ++u)
#pragma unroll
          for (int v = 0; v < 5; ++v) win[u][v] = Yt[r + d + u][v];
        for (int k = 0; k < 12; ++k) {
          if (k > 0) {
#pragma unroll
            for (int u = 0; u < 5; ++u) {
#pragma unroll
              for (int v = 0; v < 4; ++v) win[u][v] = win[u][v + 1];
              win[u][4] = Yt[r + d + u][k + 4];
            }
          }
          float dot = 0.f;
#pragma unroll
          for (int u = 0; u < 5; ++u)
#pragma unroll
            for (int v = 0; v < 5; ++v) dot += xp[u][v] * win[u][v];
          float muYv = mY[r + d][k], ivYv = iY[r + d][k];
          float ncc = (dot - 25.f * muXv * muYv) * ivXv * ivYv * 0.04f;
          float rv = fmaxf(ncc, 0.f);
          const float* wo = wbase + d * 12 + k;
#pragma unroll
          for (int o = 0; o < 25; ++o) acc[o] += wo[o * 1500] * rv;
        }
      }
    }
  }

  if (active) {
    int i = i0 + r;
    float* p = part + ((long)(b * 5 + cz) * 25) * 444 + i * 12 + j;
#pragma unroll
    for (int o = 0; o < 25; ++o) p[o * 444] = acc[o];
  }
}

// ---------------- sum partials + bias + relu -> red1out ----------------
__global__ __launch_bounds__(256) void k_red1sum(
    const float* __restrict__ part, const float* __restrict__ b1,
    float* __restrict__ red1) {
  int b = blockIdx.x;
  for (int item = threadIdx.x; item < 25 * 444; item += 256) {
    int o = item / 444, px = item % 444;
    float s = b1[o];
#pragma unroll
    for (int cz = 0; cz < 5; ++cz)
      s += part[((long)(b * 5 + cz) * 25 + o) * 444 + px];
    red1[((long)b * 25 + o) * 444 + px] = fmaxf(s, 0.f);
  }
}

// ---------------- red2 3x3 conv + pool ----------------
__global__ __launch_bounds__(256) void k_red2(
    const float* __restrict__ red1, const float* __restrict__ w,
    const float* __restrict__ bias, float* __restrict__ r2p) {
  int b = blockIdx.x;
  __shared__ float inb[25 * 444];
  __shared__ float wl[25 * 25 * 9];
  for (int idx = threadIdx.x; idx < 25 * 444; idx += 256)
    inb[idx] = red1[(long)b * 25 * 444 + idx];
  for (int idx = threadIdx.x; idx < 25 * 25 * 9; idx += 256)
    wl[idx] = w[idx];
  __syncthreads();
  for (int item = threadIdx.x; item < 25 * 85; item += 256) {
    int oc = item / 85, rem = item % 85;
    int pi = rem / 5, pj = rem % 5;
    int ci0 = 2 * pi, cj0 = 2 * pj;   // conv coords: rows ci0..ci0+1 (<35), cols cj0..cj0+1 (<10)
    float a00 = 0, a01 = 0, a10 = 0, a11 = 0;
    for (int ic = 0; ic < 25; ++ic) {
      const float* xp = inb + ic * 444 + ci0 * 12 + cj0;
      float win[4][4];
#pragma unroll
      for (int u = 0; u < 4; ++u)
#pragma unroll
        for (int v = 0; v < 4; ++v) win[u][v] = xp[u * 12 + v];
      const float* wq = wl + (oc * 25 + ic) * 9;
#pragma unroll
      for (int u = 0; u < 3; ++u)
#pragma unroll
        for (int v = 0; v < 3; ++v) {
          float wv = wq[u * 3 + v];
          a00 += wv * win[u][v];
          a01 += wv * win[u][v + 1];
          a10 += wv * win[u + 1][v];
          a11 += wv * win[u + 1][v + 1];
        }
    }
    float mx = fmaxf(fmaxf(a00, a01), fmaxf(a10, a11));
    r2p[(long)b * 2125 + item] = mx + bias[oc];   // no relu after red2
  }
}

// ---------------- lin1 + lin2 ----------------
__global__ __launch_bounds__(512) void k_lin(
    const float* __restrict__ r2p, const float* __restrict__ wlt,
    const float* __restrict__ b1, const float* __restrict__ w2,
    const float* __restrict__ b2, float* __restrict__ out) {
  int b = blockIdx.x;
  __shared__ float xv[2125];
  __shared__ float o1[500];
  for (int idx = threadIdx.x; idx < 2125; idx += 512)
    xv[idx] = r2p[(long)b * 2125 + idx];
  __syncthreads();
  int o = threadIdx.x;
  if (o < 500) {
    float acc = b1[o];
    for (int t = 0; t < 2125; ++t) acc += xv[t] * wlt[(long)t * 500 + o];
    o1[o] = acc;
  }
  __syncthreads();
  if (o < 2) {
    float acc = b2[o];
    for (int t = 0; t < 500; ++t) acc += o1[t] * w2[o * 500 + t];
    out[b * 2 + o] = acc;
  }
}

// ---------------- launch ----------------
extern "C" void kernel_launch(void* const* d_in, const int* in_sizes, int n_in,
                              void* d_out, int out_size, void* d_ws, size_t ws_size,
                              hipStream_t stream) {
  const float* x1   = (const float*)d_in[0];
  const float* x2   = (const float*)d_in[1];
  const float* w1   = (const float*)d_in[2];
  const float* b1   = (const float*)d_in[3];
  const float* w2   = (const float*)d_in[4];
  const float* b2   = (const float*)d_in[5];
  const float* wr1  = (const float*)d_in[6];
  const float* br1  = (const float*)d_in[7];
  const float* wr2  = (const float*)d_in[8];
  const float* br2  = (const float*)d_in[9];
  const float* wl1  = (const float*)d_in[10];
  const float* bl1  = (const float*)d_in[11];
  const float* wl2  = (const float*)d_in[12];
  const float* bl2  = (const float*)d_in[13];
  float* out = (float*)d_out;
  float* ws  = (float*)d_ws;

  float* c1   = ws + OFF_C1;
  float* f    = ws + OFF_F;
  float* mu   = ws + OFF_MU;
  float* iv   = ws + OFF_IV;
  float* wlt  = ws + OFF_WLT;
  float* part = ws + OFF_PART;
  float* red1 = ws + OFF_RED1;
  float* r2p  = ws + OFF_R2P;

  hipLaunchKernelGGL(k_wt, dim3((2125 * 500 + 255) / 256), dim3(256), 0, stream, wl1, wlt);
  hipLaunchKernelGGL(k_conv1, dim3(128, 20), dim3(256), 0, stream, x1, x2, w1, b1, c1);
  hipLaunchKernelGGL(k_conv2, dim3(128, 25), dim3(256), 0, stream, c1, w2, b2, f);
  hipLaunchKernelGGL(k_stats, dim3(128, 25), dim3(448), 0, stream, f, mu, iv);
  hipLaunchKernelGGL(k_ncc, dim3(64, 4, 5), dim3(128), 0, stream, f, mu, iv, wr1, part);
  hipLaunchKernelGGL(k_red1sum, dim3(64), dim3(256), 0, stream, part, br1, red1);
  hipLaunchKernelGGL(k_red2, dim3(64), dim3(256), 0, stream, red1, wr2, br2, r2p);
  hipLaunchKernelGGL(k_lin, dim3(64), dim3(512), 0, stream, r2p, wlt, bl1, wl2, bl2, out);
}

// Round 3
// 641.205 us; speedup vs baseline: 1.2317x; 1.2317x over previous
//
#include <hip/hip_runtime.h>
#include <math.h>

// ---------------- geometry ----------------
// x: [img][3][160][60], img 0..127 (0..63 = x1, 64..127 = x2)
// conv1 5x5 VALID -> [20][156][56], relu, pool2 -> [20][78][28]
// conv2 5x5 VALID -> [25][74][24], relu, pool2 -> f [25][37][12]
// stats: mu, inv = 1/(std+0.01) per (img,c,i,j) over zero-padded 5x5 patch
// ncc = (dot - 25 muX muY) * invX * invY / 25 ; relu; 1x1 conv w_red1 -> [64][25][37][12]
// red2 3x3 VALID -> [35][10], pool2 -> [17][5]; flatten 2125; lin1 2125->500; lin2 500->2

// ws offsets in floats
static const long OFF_C1   = 0;          // [128][20][78][28] = 5,591,040
static const long OFF_F    = 5591040;    // [128][25][444]    = 1,420,800
static const long OFF_MU   = 7011840;    // [128][25][444]
static const long OFF_IV   = 8432640;    // [128][25][444]
static const long OFF_WLT  = 9853440;    // [2125][500]       = 1,062,500
static const long OFF_PART = 0;          // overlay c1: [64][5][25][444] = 3,552,000
static const long OFF_RED1 = 3552000;    // [64][25][444] = 710,400
static const long OFF_R2P  = 4262400;    // [64][2125]    = 136,000

// ---------------- w_lin1 transpose: wlt[t][o] = wl1[o][t] ----------------
__global__ void k_wt(const float* __restrict__ wl1, float* __restrict__ wlt) {
  long idx = (long)blockIdx.x * 256 + threadIdx.x;
  if (idx < 2125L * 500) {
    long t = idx / 500, o = idx % 500;
    wlt[idx] = wl1[o * 2125 + t];
  }
}

// ---------------- conv1 + relu + pool (oc register-blocked) ----------------
__global__ __launch_bounds__(256) void k_conv1(
    const float* __restrict__ x1, const float* __restrict__ x2,
    const float* __restrict__ w, const float* __restrict__ bias,
    float* __restrict__ out) {
  int img = blockIdx.x;
  int g   = blockIdx.y;          // 0..5, 13 pooled rows each (78 = 6*13)
  int p0  = g * 13;
  const float* x = (img < 64) ? (x1 + (long)img * 28800)
                              : (x2 + (long)(img - 64) * 28800);
  for (int item = threadIdx.x; item < 13 * 28; item += 256) {
    int r = item / 28, j = item % 28;
    int ci0 = 2 * (p0 + r), cj0 = 2 * j;
    float acc[20][4];
#pragma unroll
    for (int o = 0; o < 20; ++o) {
      acc[o][0] = 0.f; acc[o][1] = 0.f; acc[o][2] = 0.f; acc[o][3] = 0.f;
    }
    for (int ic = 0; ic < 3; ++ic) {
      const float* xp = x + (long)ic * 9600 + ci0 * 60 + cj0;
      float win[6][6];
#pragma unroll
      for (int u = 0; u < 6; ++u)
#pragma unroll
        for (int v = 0; v < 6; ++v) win[u][v] = xp[u * 60 + v];
#pragma unroll
      for (int o = 0; o < 20; ++o) {
        const float* wq = w + (o * 3 + ic) * 25;
#pragma unroll
        for (int u = 0; u < 5; ++u)
#pragma unroll
          for (int v = 0; v < 5; ++v) {
            float wv = wq[u * 5 + v];
            acc[o][0] += wv * win[u][v];
            acc[o][1] += wv * win[u][v + 1];
            acc[o][2] += wv * win[u + 1][v];
            acc[o][3] += wv * win[u + 1][v + 1];
          }
      }
    }
#pragma unroll
    for (int o = 0; o < 20; ++o) {
      float mx = fmaxf(fmaxf(acc[o][0], acc[o][1]), fmaxf(acc[o][2], acc[o][3]));
      out[((long)img * 20 + o) * 2184 + (p0 + r) * 28 + j] = fmaxf(mx + bias[o], 0.f);
    }
  }
}

// ---------------- conv2 + relu + pool (oc register-blocked) ----------------
__global__ __launch_bounds__(128) void k_conv2(
    const float* __restrict__ in, const float* __restrict__ w,
    const float* __restrict__ bias, float* __restrict__ out) {
  int img = blockIdx.x;
  int g   = blockIdx.y;          // 0..3 -> pooled rows p0..p0+9 (last: 7)
  int p0  = g * 10;
  int ROWS = min(10, 37 - p0);
  int tid = threadIdx.x;
  int r = tid / 12, j = tid % 12;
  if (tid >= 120 || r >= ROWS) return;
  const float* x = in + (long)img * 20 * 2184;
  int ci0 = 2 * (p0 + r), cj0 = 2 * j;
  float acc[25][4];
#pragma unroll
  for (int o = 0; o < 25; ++o) {
    acc[o][0] = 0.f; acc[o][1] = 0.f; acc[o][2] = 0.f; acc[o][3] = 0.f;
  }
  for (int ic = 0; ic < 20; ++ic) {
    const float* xp = x + (long)ic * 2184 + ci0 * 28 + cj0;
    float win[6][6];
#pragma unroll
    for (int u = 0; u < 6; ++u)
#pragma unroll
      for (int v = 0; v < 6; ++v) win[u][v] = xp[u * 28 + v];
#pragma unroll
    for (int o = 0; o < 25; ++o) {
      const float* wq = w + (o * 20 + ic) * 25;
#pragma unroll
      for (int u = 0; u < 5; ++u)
#pragma unroll
        for (int v = 0; v < 5; ++v) {
          float wv = wq[u * 5 + v];
          acc[o][0] += wv * win[u][v];
          acc[o][1] += wv * win[u][v + 1];
          acc[o][2] += wv * win[u + 1][v];
          acc[o][3] += wv * win[u + 1][v + 1];
        }
    }
  }
#pragma unroll
  for (int o = 0; o < 25; ++o) {
    float mx = fmaxf(fmaxf(acc[o][0], acc[o][1]), fmaxf(acc[o][2], acc[o][3]));
    out[((long)img * 25 + o) * 444 + (p0 + r) * 12 + j] = fmaxf(mx + bias[o], 0.f);
  }
}

// ---------------- patch stats: mu, 1/(std+eps) ----------------
__global__ __launch_bounds__(448) void k_stats(
    const float* __restrict__ f, float* __restrict__ mu, float* __restrict__ iv) {
  int img = blockIdx.x, c = blockIdx.y;
  int t = threadIdx.x;
  if (t >= 444) return;
  int i = t / 12, j = t % 12;
  const float* fp = f + ((long)img * 25 + c) * 444;
  float s = 0.f, sq = 0.f;
#pragma unroll
  for (int u = 0; u < 5; ++u) {
    int gi = i + u - 2;
    if (gi < 0 || gi >= 37) continue;
#pragma unroll
    for (int v = 0; v < 5; ++v) {
      int gj = j + v - 2;
      if (gj < 0 || gj >= 12) continue;
      float vv = fp[gi * 12 + gj];
      s += vv;
      sq += vv * vv;
    }
  }
  float m = s * 0.04f;
  float var = sq * 0.04f - m * m;
  float sd = sqrtf(fmaxf(var, 0.f));
  long idx = ((long)img * 25 + c) * 444 + t;
  mu[idx] = m;
  iv[idx] = 1.f / (sd + 0.01f);
}

// ---------------- fused NCC + relu + red1 (partial over c-groups) ----------------
__global__ __launch_bounds__(128) void k_ncc(
    const float* __restrict__ f, const float* __restrict__ mu,
    const float* __restrict__ iv, const float* __restrict__ wr1,
    float* __restrict__ part) {
  int b  = blockIdx.x;          // 0..63
  int g  = blockIdx.y;          // 0..3 -> rows i0..i0+ROWS-1
  int cz = blockIdx.z;          // 0..4 -> channels cz*5..cz*5+4
  int i0 = g * 10;
  int ROWS = min(10, 37 - i0);
  int tid = threadIdx.x;
  int j = tid % 12, r = tid / 12;
  bool active = (r < ROWS);

  __shared__ float Xt[14][16], Yt[18][16];
  __shared__ float mX[10][12], iX[10][12], mY[14][12], iY[14][12];

  const float* Xf = f + (long)b * 25 * 444;
  const float* Yf = f + (long)(64 + b) * 25 * 444;
  const float* muX_g = mu + (long)b * 25 * 444;
  const float* ivX_g = iv + (long)b * 25 * 444;
  const float* muY_g = mu + (long)(64 + b) * 25 * 444;
  const float* ivY_g = iv + (long)(64 + b) * 25 * 444;

  float acc[25];
#pragma unroll
  for (int o = 0; o < 25; ++o) acc[o] = 0.f;

  for (int cc = 0; cc < 5; ++cc) {
    int c = cz * 5 + cc;
    __syncthreads();
    for (int idx = tid; idx < 14 * 16; idx += 128) {
      int rr = idx >> 4, cl = idx & 15;
      int gi = i0 - 2 + rr, gj = cl - 2;
      Xt[rr][cl] = (gi >= 0 && gi < 37 && gj >= 0 && gj < 12)
                       ? Xf[c * 444 + gi * 12 + gj] : 0.f;
    }
    for (int idx = tid; idx < 18 * 16; idx += 128) {
      int rr = idx >> 4, cl = idx & 15;
      int gi = i0 - 4 + rr, gj = cl - 2;
      Yt[rr][cl] = (gi >= 0 && gi < 37 && gj >= 0 && gj < 12)
                       ? Yf[c * 444 + gi * 12 + gj] : 0.f;
    }
    for (int idx = tid; idx < 120; idx += 128) {
      int rr = idx / 12, gj = idx % 12;
      int gi = i0 + rr;
      bool ok = gi < 37;
      mX[rr][gj] = ok ? muX_g[c * 444 + gi * 12 + gj] : 0.f;
      iX[rr][gj] = ok ? ivX_g[c * 444 + gi * 12 + gj] : 0.f;
    }
    for (int idx = tid; idx < 168; idx += 128) {
      int rr = idx / 12, gj = idx % 12;
      int gi = i0 - 2 + rr;
      bool ok = (gi >= 0 && gi < 37);
      mY[rr][gj] = ok ? muY_g[c * 444 + gi * 12 + gj] : 0.f;
      iY[rr][gj] = ok ? ivY_g[c * 444 + gi * 12 + gj] : 0.f;
    }
    __syncthreads();

    if (active) {
      float xp[5][5];
#pragma unroll
      for (int u = 0; u < 5; ++u)
#pragma unroll
        for (int v = 0; v < 5; ++v) xp[u][v] = Xt[r + u][j + v];
      float muXv = mX[r][j], ivXv = iX[r][j];
      const float* wbase = wr1 + c * 60;
      for (int d = 0; d < 5; ++d) {
        int yi = i0 + r + d - 2;
        if (yi < 0 || yi >= 37) continue;
        float win[5][5];
#pragma unroll
        for (int u = 0; u < 5; ++u)
#pragma unroll
          for (int v = 0; v < 5; ++v) win[u][v] = Yt[r + d + u][v];
        for (int k = 0; k < 12; ++k) {
          if (k > 0) {
#pragma unroll
            for (int u = 0; u < 5; ++u) {
#pragma unroll
              for (int v = 0; v < 4; ++v) win[u][v] = win[u][v + 1];
              win[u][4] = Yt[r + d + u][k + 4];
            }
          }
          float dot = 0.f;
#pragma unroll
          for (int u = 0; u < 5; ++u)
#pragma unroll
            for (int v = 0; v < 5; ++v) dot += xp[u][v] * win[u][v];
          float muYv = mY[r + d][k], ivYv = iY[r + d][k];
          float ncc = (dot - 25.f * muXv * muYv) * ivXv * ivYv * 0.04f;
          float rv = fmaxf(ncc, 0.f);
          const float* wo = wbase + d * 12 + k;
#pragma unroll
          for (int o = 0; o < 25; ++o) acc[o] += wo[o * 1500] * rv;
        }
      }
    }
  }

  if (active) {
    int i = i0 + r;
    float* p = part + ((long)(b * 5 + cz) * 25) * 444 + i * 12 + j;
#pragma unroll
    for (int o = 0; o < 25; ++o) p[o * 444] = acc[o];
  }
}

// ---------------- sum partials + bias + relu -> red1out ----------------
__global__ __launch_bounds__(256) void k_red1sum(
    const float* __restrict__ part, const float* __restrict__ b1,
    float* __restrict__ red1) {
  int b = blockIdx.x;
  for (int item = threadIdx.x; item < 25 * 444; item += 256) {
    int o = item / 444, px = item % 444;
    float s = b1[o];
#pragma unroll
    for (int cz = 0; cz < 5; ++cz)
      s += part[((long)(b * 5 + cz) * 25 + o) * 444 + px];
    red1[((long)b * 25 + o) * 444 + px] = fmaxf(s, 0.f);
  }
}

// ---------------- red2 3x3 conv + pool ----------------
__global__ __launch_bounds__(256) void k_red2(
    const float* __restrict__ red1, const float* __restrict__ w,
    const float* __restrict__ bias, float* __restrict__ r2p) {
  int b = blockIdx.x;
  __shared__ float inb[25 * 444];
  __shared__ float wl[25 * 25 * 9];
  for (int idx = threadIdx.x; idx < 25 * 444; idx += 256)
    inb[idx] = red1[(long)b * 25 * 444 + idx];
  for (int idx = threadIdx.x; idx < 25 * 25 * 9; idx += 256)
    wl[idx] = w[idx];
  __syncthreads();
  for (int item = threadIdx.x; item < 25 * 85; item += 256) {
    int oc = item / 85, rem = item % 85;
    int pi = rem / 5, pj = rem % 5;
    int ci0 = 2 * pi, cj0 = 2 * pj;
    float a00 = 0, a01 = 0, a10 = 0, a11 = 0;
    for (int ic = 0; ic < 25; ++ic) {
      const float* xp = inb + ic * 444 + ci0 * 12 + cj0;
      float win[4][4];
#pragma unroll
      for (int u = 0; u < 4; ++u)
#pragma unroll
        for (int v = 0; v < 4; ++v) win[u][v] = xp[u * 12 + v];
      const float* wq = wl + (oc * 25 + ic) * 9;
#pragma unroll
      for (int u = 0; u < 3; ++u)
#pragma unroll
        for (int v = 0; v < 3; ++v) {
          float wv = wq[u * 3 + v];
          a00 += wv * win[u][v];
          a01 += wv * win[u][v + 1];
          a10 += wv * win[u + 1][v];
          a11 += wv * win[u + 1][v + 1];
        }
    }
    float mx = fmaxf(fmaxf(a00, a01), fmaxf(a10, a11));
    r2p[(long)b * 2125 + item] = mx + bias[oc];   // no relu after red2
  }
}

// ---------------- lin1 + lin2 ----------------
__global__ __launch_bounds__(512) void k_lin(
    const float* __restrict__ r2p, const float* __restrict__ wlt,
    const float* __restrict__ b1, const float* __restrict__ w2,
    const float* __restrict__ b2, float* __restrict__ out) {
  int b = blockIdx.x;
  __shared__ float xv[2125];
  __shared__ float o1[500];
  for (int idx = threadIdx.x; idx < 2125; idx += 512)
    xv[idx] = r2p[(long)b * 2125 + idx];
  __syncthreads();
  int o = threadIdx.x;
  if (o < 500) {
    float acc = b1[o];
    for (int t = 0; t < 2125; ++t) acc += xv[t] * wlt[(long)t * 500 + o];
    o1[o] = acc;
  }
  __syncthreads();
  if (o < 2) {
    float acc = b2[o];
    for (int t = 0; t < 500; ++t) acc += o1[t] * w2[o * 500 + t];
    out[b * 2 + o] = acc;
  }
}

// ---------------- launch ----------------
extern "C" void kernel_launch(void* const* d_in, const int* in_sizes, int n_in,
                              void* d_out, int out_size, void* d_ws, size_t ws_size,
                              hipStream_t stream) {
  const float* x1   = (const float*)d_in[0];
  const float* x2   = (const float*)d_in[1];
  const float* w1   = (const float*)d_in[2];
  const float* b1   = (const float*)d_in[3];
  const float* w2   = (const float*)d_in[4];
  const float* b2   = (const float*)d_in[5];
  const float* wr1  = (const float*)d_in[6];
  const float* br1  = (const float*)d_in[7];
  const float* wr2  = (const float*)d_in[8];
  const float* br2  = (const float*)d_in[9];
  const float* wl1  = (const float*)d_in[10];
  const float* bl1  = (const float*)d_in[11];
  const float* wl2  = (const float*)d_in[12];
  const float* bl2  = (const float*)d_in[13];
  float* out = (float*)d_out;
  float* ws  = (float*)d_ws;

  float* c1   = ws + OFF_C1;
  float* f    = ws + OFF_F;
  float* mu   = ws + OFF_MU;
  float* iv   = ws + OFF_IV;
  float* wlt  = ws + OFF_WLT;
  float* part = ws + OFF_PART;
  float* red1 = ws + OFF_RED1;
  float* r2p  = ws + OFF_R2P;

  hipLaunchKernelGGL(k_wt, dim3((2125 * 500 + 255) / 256), dim3(256), 0, stream, wl1, wlt);
  hipLaunchKernelGGL(k_conv1, dim3(128, 6), dim3(256), 0, stream, x1, x2, w1, b1, c1);
  hipLaunchKernelGGL(k_conv2, dim3(128, 4), dim3(128), 0, stream, c1, w2, b2, f);
  hipLaunchKernelGGL(k_stats, dim3(128, 25), dim3(448), 0, stream, f, mu, iv);
  hipLaunchKernelGGL(k_ncc, dim3(64, 4, 5), dim3(128), 0, stream, f, mu, iv, wr1, part);
  hipLaunchKernelGGL(k_red1sum, dim3(64), dim3(256), 0, stream, part, br1, red1);
  hipLaunchKernelGGL(k_red2, dim3(64), dim3(256), 0, stream, red1, wr2, br2, r2p);
  hipLaunchKernelGGL(k_lin, dim3(64), dim3(512), 0, stream, r2p, wlt, bl1, wl2, bl2, out);
}

// Round 4
// 598.898 us; speedup vs baseline: 1.3187x; 1.0706x over previous
//
#include <hip/hip_runtime.h>
#include <math.h>

// ---------------- geometry ----------------
// x: [img][3][160][60], img 0..127 (0..63 = x1, 64..127 = x2)
// conv1 5x5 VALID -> [20][156][56], relu, pool2 -> [20][78][28]
// conv2 5x5 VALID -> [25][74][24], relu, pool2 -> f [25][37][12]
// stats: mu, inv = 1/(std+0.01) per (img,c,i,j) over zero-padded 5x5 patch
// ncc = (dot - 25 muX muY) * invX * invY / 25 ; relu; 1x1 conv w_red1 -> [64][25][37][12]
// red2 3x3 VALID -> [35][10], pool2 -> [17][5]; flatten 2125; lin1 2125->500; lin2 500->2

// ws offsets in floats
static const long OFF_C1   = 0;          // [128][20][78][28] = 5,591,040
static const long OFF_F    = 5591040;    // [128][25][444]    = 1,420,800
static const long OFF_MU   = 7011840;    // [128][25][444]
static const long OFF_IV   = 8432640;    // [128][25][444]
static const long OFF_WLT  = 9853440;    // [2125][500]       = 1,062,500
static const long OFF_PART = 0;          // overlay c1: [64][5][25][444] = 3,552,000
static const long OFF_RED1 = 3552000;    // [64][25][444] = 710,400
static const long OFF_R2P  = 4262400;    // [64][2125]    = 136,000

// ---------------- w_lin1 transpose: wlt[t][o] = wl1[o][t] ----------------
__global__ void k_wt(const float* __restrict__ wl1, float* __restrict__ wlt) {
  long idx = (long)blockIdx.x * 256 + threadIdx.x;
  if (idx < 2125L * 500) {
    long t = idx / 500, o = idx % 500;
    wlt[idx] = wl1[o * 2125 + t];
  }
}

// ---------------- conv1 + relu + pool (oc-group register-blocked) ----------------
template <int OC0, int NOC>
__global__ __launch_bounds__(128) void k_conv1t(
    const float* __restrict__ x1, const float* __restrict__ x2,
    const float* __restrict__ w, const float* __restrict__ bias,
    float* __restrict__ out) {
  int img = blockIdx.x;
  int g   = blockIdx.y;          // 0..5, 13 pooled rows each (78 = 6*13)
  int p0  = g * 13;
  const float* x = (img < 64) ? (x1 + (long)img * 28800)
                              : (x2 + (long)(img - 64) * 28800);
  for (int item = threadIdx.x; item < 13 * 28; item += 128) {
    int r = item / 28, j = item % 28;
    int ci0 = 2 * (p0 + r), cj0 = 2 * j;
    float acc[NOC][4];
#pragma unroll
    for (int o = 0; o < NOC; ++o) {
      acc[o][0] = 0.f; acc[o][1] = 0.f; acc[o][2] = 0.f; acc[o][3] = 0.f;
    }
    for (int ic = 0; ic < 3; ++ic) {
      const float* xp = x + (long)ic * 9600 + ci0 * 60 + cj0;
      float win[6][6];
#pragma unroll
      for (int u = 0; u < 6; ++u)
#pragma unroll
        for (int v = 0; v < 6; ++v) win[u][v] = xp[u * 60 + v];
#pragma unroll
      for (int o = 0; o < NOC; ++o) {
        const float* wq = w + ((OC0 + o) * 3 + ic) * 25;
#pragma unroll
        for (int u = 0; u < 5; ++u)
#pragma unroll
          for (int v = 0; v < 5; ++v) {
            float wv = wq[u * 5 + v];
            acc[o][0] += wv * win[u][v];
            acc[o][1] += wv * win[u][v + 1];
            acc[o][2] += wv * win[u + 1][v];
            acc[o][3] += wv * win[u + 1][v + 1];
          }
      }
    }
#pragma unroll
    for (int o = 0; o < NOC; ++o) {
      float mx = fmaxf(fmaxf(acc[o][0], acc[o][1]), fmaxf(acc[o][2], acc[o][3]));
      out[((long)img * 20 + OC0 + o) * 2184 + (p0 + r) * 28 + j] =
          fmaxf(mx + bias[OC0 + o], 0.f);
    }
  }
}

// ---------------- conv2 + relu + pool (oc-group register-blocked) ----------------
template <int OC0, int NOC>
__global__ __launch_bounds__(128) void k_conv2t(
    const float* __restrict__ in, const float* __restrict__ w,
    const float* __restrict__ bias, float* __restrict__ out) {
  int img = blockIdx.x;
  int g   = blockIdx.y;          // 0..3 -> pooled rows p0..p0+9 (last: 7)
  int p0  = g * 10;
  int ROWS = min(10, 37 - p0);
  int tid = threadIdx.x;
  int r = tid / 12, j = tid % 12;
  if (tid >= 120 || r >= ROWS) return;
  const float* x = in + (long)img * 20 * 2184;
  int ci0 = 2 * (p0 + r), cj0 = 2 * j;
  float acc[NOC][4];
#pragma unroll
  for (int o = 0; o < NOC; ++o) {
    acc[o][0] = 0.f; acc[o][1] = 0.f; acc[o][2] = 0.f; acc[o][3] = 0.f;
  }
  for (int ic = 0; ic < 20; ++ic) {
    const float* xp = x + (long)ic * 2184 + ci0 * 28 + cj0;
    float win[6][6];
#pragma unroll
    for (int u = 0; u < 6; ++u)
#pragma unroll
      for (int v = 0; v < 6; ++v) win[u][v] = xp[u * 28 + v];
#pragma unroll
    for (int o = 0; o < NOC; ++o) {
      const float* wq = w + ((OC0 + o) * 20 + ic) * 25;
#pragma unroll
      for (int u = 0; u < 5; ++u)
#pragma unroll
        for (int v = 0; v < 5; ++v) {
          float wv = wq[u * 5 + v];
          acc[o][0] += wv * win[u][v];
          acc[o][1] += wv * win[u][v + 1];
          acc[o][2] += wv * win[u + 1][v];
          acc[o][3] += wv * win[u + 1][v + 1];
        }
    }
  }
#pragma unroll
  for (int o = 0; o < NOC; ++o) {
    float mx = fmaxf(fmaxf(acc[o][0], acc[o][1]), fmaxf(acc[o][2], acc[o][3]));
    out[((long)img * 25 + OC0 + o) * 444 + (p0 + r) * 12 + j] =
        fmaxf(mx + bias[OC0 + o], 0.f);
  }
}

// ---------------- patch stats: mu, 1/(std+eps) ----------------
__global__ __launch_bounds__(448) void k_stats(
    const float* __restrict__ f, float* __restrict__ mu, float* __restrict__ iv) {
  int img = blockIdx.x, c = blockIdx.y;
  int t = threadIdx.x;
  if (t >= 444) return;
  int i = t / 12, j = t % 12;
  const float* fp = f + ((long)img * 25 + c) * 444;
  float s = 0.f, sq = 0.f;
#pragma unroll
  for (int u = 0; u < 5; ++u) {
    int gi = i + u - 2;
    if (gi < 0 || gi >= 37) continue;
#pragma unroll
    for (int v = 0; v < 5; ++v) {
      int gj = j + v - 2;
      if (gj < 0 || gj >= 12) continue;
      float vv = fp[gi * 12 + gj];
      s += vv;
      sq += vv * vv;
    }
  }
  float m = s * 0.04f;
  float var = sq * 0.04f - m * m;
  float sd = sqrtf(fmaxf(var, 0.f));
  long idx = ((long)img * 25 + c) * 444 + t;
  mu[idx] = m;
  iv[idx] = 1.f / (sd + 0.01f);
}

// ---------------- fused NCC + relu + red1 (partial over c-groups) ----------------
__global__ __launch_bounds__(128) void k_ncc(
    const float* __restrict__ f, const float* __restrict__ mu,
    const float* __restrict__ iv, const float* __restrict__ wr1,
    float* __restrict__ part) {
  int b  = blockIdx.x;          // 0..63
  int g  = blockIdx.y;          // 0..3 -> rows i0..i0+ROWS-1
  int cz = blockIdx.z;          // 0..4 -> channels cz*5..cz*5+4
  int i0 = g * 10;
  int ROWS = min(10, 37 - i0);
  int tid = threadIdx.x;
  int j = tid % 12, r = tid / 12;
  bool active = (r < ROWS);

  __shared__ float Xt[14][16], Yt[18][16];
  __shared__ float mX[10][12], iX[10][12], mY[14][12], iY[14][12];

  const float* Xf = f + (long)b * 25 * 444;
  const float* Yf = f + (long)(64 + b) * 25 * 444;
  const float* muX_g = mu + (long)b * 25 * 444;
  const float* ivX_g = iv + (long)b * 25 * 444;
  const float* muY_g = mu + (long)(64 + b) * 25 * 444;
  const float* ivY_g = iv + (long)(64 + b) * 25 * 444;

  float acc[25];
#pragma unroll
  for (int o = 0; o < 25; ++o) acc[o] = 0.f;

  for (int cc = 0; cc < 5; ++cc) {
    int c = cz * 5 + cc;
    __syncthreads();
    for (int idx = tid; idx < 14 * 16; idx += 128) {
      int rr = idx >> 4, cl = idx & 15;
      int gi = i0 - 2 + rr, gj = cl - 2;
      Xt[rr][cl] = (gi >= 0 && gi < 37 && gj >= 0 && gj < 12)
                       ? Xf[c * 444 + gi * 12 + gj] : 0.f;
    }
    for (int idx = tid; idx < 18 * 16; idx += 128) {
      int rr = idx >> 4, cl = idx & 15;
      int gi = i0 - 4 + rr, gj = cl - 2;
      Yt[rr][cl] = (gi >= 0 && gi < 37 && gj >= 0 && gj < 12)
                       ? Yf[c * 444 + gi * 12 + gj] : 0.f;
    }
    for (int idx = tid; idx < 120; idx += 128) {
      int rr = idx / 12, gj = idx % 12;
      int gi = i0 + rr;
      bool ok = gi < 37;
      mX[rr][gj] = ok ? muX_g[c * 444 + gi * 12 + gj] : 0.f;
      iX[rr][gj] = ok ? ivX_g[c * 444 + gi * 12 + gj] : 0.f;
    }
    for (int idx = tid; idx < 168; idx += 128) {
      int rr = idx / 12, gj = idx % 12;
      int gi = i0 - 2 + rr;
      bool ok = (gi >= 0 && gi < 37);
      mY[rr][gj] = ok ? muY_g[c * 444 + gi * 12 + gj] : 0.f;
      iY[rr][gj] = ok ? ivY_g[c * 444 + gi * 12 + gj] : 0.f;
    }
    __syncthreads();

    if (active) {
      float xp[5][5];
#pragma unroll
      for (int u = 0; u < 5; ++u)
#pragma unroll
        for (int v = 0; v < 5; ++v) xp[u][v] = Xt[r + u][j + v];
      float muXv = mX[r][j], ivXv = iX[r][j];
      const float* wbase = wr1 + c * 60;
      for (int d = 0; d < 5; ++d) {
        int yi = i0 + r + d - 2;
        if (yi < 0 || yi >= 37) continue;
        float win[5][5];
#pragma unroll
        for (int u = 0; u < 5; ++u)
#pragma unroll
          for (int v = 0; v < 5; ++v) win[u][v] = Yt[r + d + u][v];
        for (int k = 0; k < 12; ++k) {
          if (k > 0) {
#pragma unroll
            for (int u = 0; u < 5; ++u) {
#pragma unroll
              for (int v = 0; v < 4; ++v) win[u][v] = win[u][v + 1];
              win[u][4] = Yt[r + d + u][k + 4];
            }
          }
          float dot = 0.f;
#pragma unroll
          for (int u = 0; u < 5; ++u)
#pragma unroll
            for (int v = 0; v < 5; ++v) dot += xp[u][v] * win[u][v];
          float muYv = mY[r + d][k], ivYv = iY[r + d][k];
          float ncc = (dot - 25.f * muXv * muYv) * ivXv * ivYv * 0.04f;
          float rv = fmaxf(ncc, 0.f);
          const float* wo = wbase + d * 12 + k;
#pragma unroll
          for (int o = 0; o < 25; ++o) acc[o] += wo[o * 1500] * rv;
        }
      }
    }
  }

  if (active) {
    int i = i0 + r;
    float* p = part + ((long)(b * 5 + cz) * 25) * 444 + i * 12 + j;
#pragma unroll
    for (int o = 0; o < 25; ++o) p[o * 444] = acc[o];
  }
}

// ---------------- sum partials + bias + relu -> red1out ----------------
__global__ __launch_bounds__(256) void k_red1sum(
    const float* __restrict__ part, const float* __restrict__ b1,
    float* __restrict__ red1) {
  int b = blockIdx.x;
  for (int item = threadIdx.x; item < 25 * 444; item += 256) {
    int o = item / 444, px = item % 444;
    float s = b1[o];
#pragma unroll
    for (int cz = 0; cz < 5; ++cz)
      s += part[((long)(b * 5 + cz) * 25 + o) * 444 + px];
    red1[((long)b * 25 + o) * 444 + px] = fmaxf(s, 0.f);
  }
}

// ---------------- red2 3x3 conv + pool ----------------
__global__ __launch_bounds__(256) void k_red2(
    const float* __restrict__ red1, const float* __restrict__ w,
    const float* __restrict__ bias, float* __restrict__ r2p) {
  int b = blockIdx.x;
  __shared__ float inb[25 * 444];
  __shared__ float wl[25 * 25 * 9];
  for (int idx = threadIdx.x; idx < 25 * 444; idx += 256)
    inb[idx] = red1[(long)b * 25 * 444 + idx];
  for (int idx = threadIdx.x; idx < 25 * 25 * 9; idx += 256)
    wl[idx] = w[idx];
  __syncthreads();
  for (int item = threadIdx.x; item < 25 * 85; item += 256) {
    int oc = item / 85, rem = item % 85;
    int pi = rem / 5, pj = rem % 5;
    int ci0 = 2 * pi, cj0 = 2 * pj;
    float a00 = 0, a01 = 0, a10 = 0, a11 = 0;
    for (int ic = 0; ic < 25; ++ic) {
      const float* xp = inb + ic * 444 + ci0 * 12 + cj0;
      float win[4][4];
#pragma unroll
      for (int u = 0; u < 4; ++u)
#pragma unroll
        for (int v = 0; v < 4; ++v) win[u][v] = xp[u * 12 + v];
      const float* wq = wl + (oc * 25 + ic) * 9;
#pragma unroll
      for (int u = 0; u < 3; ++u)
#pragma unroll
        for (int v = 0; v < 3; ++v) {
          float wv = wq[u * 3 + v];
          a00 += wv * win[u][v];
          a01 += wv * win[u][v + 1];
          a10 += wv * win[u + 1][v];
          a11 += wv * win[u + 1][v + 1];
        }
    }
    float mx = fmaxf(fmaxf(a00, a01), fmaxf(a10, a11));
    r2p[(long)b * 2125 + item] = mx + bias[oc];   // no relu after red2
  }
}

// ---------------- lin1 + lin2 ----------------
__global__ __launch_bounds__(512) void k_lin(
    const float* __restrict__ r2p, const float* __restrict__ wlt,
    const float* __restrict__ b1, const float* __restrict__ w2,
    const float* __restrict__ b2, float* __restrict__ out) {
  int b = blockIdx.x;
  __shared__ float xv[2125];
  __shared__ float o1[500];
  for (int idx = threadIdx.x; idx < 2125; idx += 512)
    xv[idx] = r2p[(long)b * 2125 + idx];
  __syncthreads();
  int o = threadIdx.x;
  if (o < 500) {
    float acc = b1[o];
    for (int t = 0; t < 2125; ++t) acc += xv[t] * wlt[(long)t * 500 + o];
    o1[o] = acc;
  }
  __syncthreads();
  if (o < 2) {
    float acc = b2[o];
    for (int t = 0; t < 500; ++t) acc += o1[t] * w2[o * 500 + t];
    out[b * 2 + o] = acc;
  }
}

// ---------------- launch ----------------
extern "C" void kernel_launch(void* const* d_in, const int* in_sizes, int n_in,
                              void* d_out, int out_size, void* d_ws, size_t ws_size,
                              hipStream_t stream) {
  const float* x1   = (const float*)d_in[0];
  const float* x2   = (const float*)d_in[1];
  const float* w1   = (const float*)d_in[2];
  const float* b1   = (const float*)d_in[3];
  const float* w2   = (const float*)d_in[4];
  const float* b2   = (const float*)d_in[5];
  const float* wr1  = (const float*)d_in[6];
  const float* br1  = (const float*)d_in[7];
  const float* wr2  = (const float*)d_in[8];
  const float* br2  = (const float*)d_in[9];
  const float* wl1  = (const float*)d_in[10];
  const float* bl1  = (const float*)d_in[11];
  const float* wl2  = (const float*)d_in[12];
  const float* bl2  = (const float*)d_in[13];
  float* out = (float*)d_out;
  float* ws  = (float*)d_ws;

  float* c1   = ws + OFF_C1;
  float* f    = ws + OFF_F;
  float* mu   = ws + OFF_MU;
  float* iv   = ws + OFF_IV;
  float* wlt  = ws + OFF_WLT;
  float* part = ws + OFF_PART;
  float* red1 = ws + OFF_RED1;
  float* r2p  = ws + OFF_R2P;

  hipLaunchKernelGGL(k_wt, dim3((2125 * 500 + 255) / 256), dim3(256), 0, stream, wl1, wlt);

  hipLaunchKernelGGL((k_conv1t<0, 7>),  dim3(128, 6), dim3(128), 0, stream, x1, x2, w1, b1, c1);
  hipLaunchKernelGGL((k_conv1t<7, 7>),  dim3(128, 6), dim3(128), 0, stream, x1, x2, w1, b1, c1);
  hipLaunchKernelGGL((k_conv1t<14, 6>), dim3(128, 6), dim3(128), 0, stream, x1, x2, w1, b1, c1);

  hipLaunchKernelGGL((k_conv2t<0, 7>),  dim3(128, 4), dim3(128), 0, stream, c1, w2, b2, f);
  hipLaunchKernelGGL((k_conv2t<7, 6>),  dim3(128, 4), dim3(128), 0, stream, c1, w2, b2, f);
  hipLaunchKernelGGL((k_conv2t<13, 6>), dim3(128, 4), dim3(128), 0, stream, c1, w2, b2, f);
  hipLaunchKernelGGL((k_conv2t<19, 6>), dim3(128, 4), dim3(128), 0, stream, c1, w2, b2, f);

  hipLaunchKernelGGL(k_stats, dim3(128, 25), dim3(448), 0, stream, f, mu, iv);
  hipLaunchKernelGGL(k_ncc, dim3(64, 4, 5), dim3(128), 0, stream, f, mu, iv, wr1, part);
  hipLaunchKernelGGL(k_red1sum, dim3(64), dim3(256), 0, stream, part, br1, red1);
  hipLaunchKernelGGL(k_red2, dim3(64), dim3(256), 0, stream, red1, wr2, br2, r2p);
  hipLaunchKernelGGL(k_lin, dim3(64), dim3(512), 0, stream, r2p, wlt, bl1, wl2, bl2, out);
}

// Round 5
// 471.329 us; speedup vs baseline: 1.6757x; 1.2707x over previous
//
#include <hip/hip_runtime.h>
#include <math.h>

// ---------------- geometry ----------------
// x: [img][3][160][60], img 0..127 (0..63 = x1, 64..127 = x2)
// conv1 5x5 VALID -> [20][156][56], relu, pool2 -> [20][78][28]
// conv2 5x5 VALID -> [25][74][24], relu, pool2 -> f [25][37][12]
// stats: mu, inv = 1/(std+0.01) per (img,c,i,j) over zero-padded 5x5 patch
// ncc = (dot - 25 muX muY) * invX * invY / 25 ; relu; 1x1 conv w_red1 -> [64][25][37][12]
// red2 3x3 VALID -> [35][10], pool2 -> [17][5]; flatten 2125; lin1 2125->500; lin2 500->2

// ws offsets in floats
static const long OFF_C1   = 0;          // [128][20][78][28] = 5,591,040
static const long OFF_F    = 5591040;    // [128][25][444]    = 1,420,800
static const long OFF_MU   = 7011840;    // [128][25][444]
static const long OFF_IV   = 8432640;    // [128][25][444]
static const long OFF_WLT  = 9853440;    // [2125][500]       = 1,062,500
// overlays of the dead-c1 region (valid after conv2 completes):
static const long OFF_PART = 0;          // ncc partials [64][5][25][444] = 3,552,000
static const long OFF_RED1 = 3552000;    // [64][25][444] = 710,400
static const long OFF_R2P  = 4262400;    // [64][2125]    = 136,000 (ends 4,398,400)
static const long OFF_WR1T = 4500000;    // [1500][25] = 37,500 (written after conv2)
static const long OFF_LINP = 0;          // lin1 partials [17][64][512] = 557,056 (after red2)

// ---------------- w_lin1 transpose: wlt[t][o] = wl1[o][t] ----------------
__global__ void k_wt(const float* __restrict__ wl1, float* __restrict__ wlt) {
  long idx = (long)blockIdx.x * 256 + threadIdx.x;
  if (idx < 2125L * 500) {
    long t = idx / 500, o = idx % 500;
    wlt[idx] = wl1[o * 2125 + t];
  }
}

// ---------------- w_red1 transpose: wr1t[(c*60+d*12+k)*25+o] ----------------
__global__ void k_wrt(const float* __restrict__ wr1, float* __restrict__ wr1t) {
  int idx = blockIdx.x * 256 + threadIdx.x;
  if (idx < 37500) {
    int o = idx / 1500, t = idx % 1500;
    wr1t[t * 25 + o] = wr1[idx];
  }
}

// ---------------- conv1 + relu + pool (oc-group register-blocked) ----------------
template <int OC0, int NOC>
__global__ __launch_bounds__(128) void k_conv1t(
    const float* __restrict__ x1, const float* __restrict__ x2,
    const float* __restrict__ w, const float* __restrict__ bias,
    float* __restrict__ out) {
  int img = blockIdx.x;
  int g   = blockIdx.y;          // 0..5, 13 pooled rows each (78 = 6*13)
  int p0  = g * 13;
  const float* x = (img < 64) ? (x1 + (long)img * 28800)
                              : (x2 + (long)(img - 64) * 28800);
  for (int item = threadIdx.x; item < 13 * 28; item += 128) {
    int r = item / 28, j = item % 28;
    int ci0 = 2 * (p0 + r), cj0 = 2 * j;
    float acc[NOC][4];
#pragma unroll
    for (int o = 0; o < NOC; ++o) {
      acc[o][0] = 0.f; acc[o][1] = 0.f; acc[o][2] = 0.f; acc[o][3] = 0.f;
    }
    for (int ic = 0; ic < 3; ++ic) {
      const float* xp = x + (long)ic * 9600 + ci0 * 60 + cj0;
      float win[6][6];
#pragma unroll
      for (int u = 0; u < 6; ++u)
#pragma unroll
        for (int v = 0; v < 6; ++v) win[u][v] = xp[u * 60 + v];
#pragma unroll
      for (int o = 0; o < NOC; ++o) {
        const float* wq = w + ((OC0 + o) * 3 + ic) * 25;
#pragma unroll
        for (int u = 0; u < 5; ++u)
#pragma unroll
          for (int v = 0; v < 5; ++v) {
            float wv = wq[u * 5 + v];
            acc[o][0] += wv * win[u][v];
            acc[o][1] += wv * win[u][v + 1];
            acc[o][2] += wv * win[u + 1][v];
            acc[o][3] += wv * win[u + 1][v + 1];
          }
      }
    }
#pragma unroll
    for (int o = 0; o < NOC; ++o) {
      float mx = fmaxf(fmaxf(acc[o][0], acc[o][1]), fmaxf(acc[o][2], acc[o][3]));
      out[((long)img * 20 + OC0 + o) * 2184 + (p0 + r) * 28 + j] =
          fmaxf(mx + bias[OC0 + o], 0.f);
    }
  }
}

// ---------------- conv2 + relu + pool (oc-group register-blocked) ----------------
template <int OC0, int NOC>
__global__ __launch_bounds__(128) void k_conv2t(
    const float* __restrict__ in, const float* __restrict__ w,
    const float* __restrict__ bias, float* __restrict__ out) {
  int img = blockIdx.x;
  int g   = blockIdx.y;          // 0..3 -> pooled rows p0..p0+9 (last: 7)
  int p0  = g * 10;
  int ROWS = min(10, 37 - p0);
  int tid = threadIdx.x;
  int r = tid / 12, j = tid % 12;
  if (tid >= 120 || r >= ROWS) return;
  const float* x = in + (long)img * 20 * 2184;
  int ci0 = 2 * (p0 + r), cj0 = 2 * j;
  float acc[NOC][4];
#pragma unroll
  for (int o = 0; o < NOC; ++o) {
    acc[o][0] = 0.f; acc[o][1] = 0.f; acc[o][2] = 0.f; acc[o][3] = 0.f;
  }
  for (int ic = 0; ic < 20; ++ic) {
    const float* xp = x + (long)ic * 2184 + ci0 * 28 + cj0;
    float win[6][6];
#pragma unroll
    for (int u = 0; u < 6; ++u)
#pragma unroll
      for (int v = 0; v < 6; ++v) win[u][v] = xp[u * 28 + v];
#pragma unroll
    for (int o = 0; o < NOC; ++o) {
      const float* wq = w + ((OC0 + o) * 20 + ic) * 25;
#pragma unroll
      for (int u = 0; u < 5; ++u)
#pragma unroll
        for (int v = 0; v < 5; ++v) {
          float wv = wq[u * 5 + v];
          acc[o][0] += wv * win[u][v];
          acc[o][1] += wv * win[u][v + 1];
          acc[o][2] += wv * win[u + 1][v];
          acc[o][3] += wv * win[u + 1][v + 1];
        }
    }
  }
#pragma unroll
  for (int o = 0; o < NOC; ++o) {
    float mx = fmaxf(fmaxf(acc[o][0], acc[o][1]), fmaxf(acc[o][2], acc[o][3]));
    out[((long)img * 25 + OC0 + o) * 444 + (p0 + r) * 12 + j] =
        fmaxf(mx + bias[OC0 + o], 0.f);
  }
}

// ---------------- patch stats: mu, 1/(std+eps) ----------------
__global__ __launch_bounds__(448) void k_stats(
    const float* __restrict__ f, float* __restrict__ mu, float* __restrict__ iv) {
  int img = blockIdx.x, c = blockIdx.y;
  int t = threadIdx.x;
  if (t >= 444) return;
  int i = t / 12, j = t % 12;
  const float* fp = f + ((long)img * 25 + c) * 444;
  float s = 0.f, sq = 0.f;
#pragma unroll
  for (int u = 0; u < 5; ++u) {
    int gi = i + u - 2;
    if (gi < 0 || gi >= 37) continue;
#pragma unroll
    for (int v = 0; v < 5; ++v) {
      int gj = j + v - 2;
      if (gj < 0 || gj >= 12) continue;
      float vv = fp[gi * 12 + gj];
      s += vv;
      sq += vv * vv;
    }
  }
  float m = s * 0.04f;
  float var = sq * 0.04f - m * m;
  float sd = sqrtf(fmaxf(var, 0.f));
  long idx = ((long)img * 25 + c) * 444 + t;
  mu[idx] = m;
  iv[idx] = 1.f / (sd + 0.01f);
}

// ---------------- fused NCC + relu + red1 (partial over c-groups) ----------------
// All 5 channels staged in LDS up-front; single barrier; weights via wr1t
// (contiguous 25 floats per (c,d,k) -> wave-uniform scalar loads).
__global__ __launch_bounds__(128) void k_ncc(
    const float* __restrict__ f, const float* __restrict__ mu,
    const float* __restrict__ iv, const float* __restrict__ wr1t,
    float* __restrict__ part) {
  int b  = blockIdx.x;          // 0..63
  int g  = blockIdx.y;          // 0..3 -> rows i0..i0+ROWS-1
  int cz = blockIdx.z;          // 0..4 -> channels cz*5..cz*5+4
  int i0 = g * 10;
  int ROWS = min(10, 37 - i0);
  int tid = threadIdx.x;
  int j = tid % 12, r = tid / 12;
  bool active = (r < ROWS);

  __shared__ float Xt[5][14][16], Yt[5][18][16];
  __shared__ float mX[5][10][12], iX[5][10][12], mY[5][14][12], iY[5][14][12];

  const float* Xf = f + (long)b * 25 * 444;
  const float* Yf = f + (long)(64 + b) * 25 * 444;
  const float* muX_g = mu + (long)b * 25 * 444;
  const float* ivX_g = iv + (long)b * 25 * 444;
  const float* muY_g = mu + (long)(64 + b) * 25 * 444;
  const float* ivY_g = iv + (long)(64 + b) * 25 * 444;

  // ---- stage all 5 channels ----
  for (int cc = 0; cc < 5; ++cc) {
    int c = cz * 5 + cc;
    for (int idx = tid; idx < 14 * 16; idx += 128) {
      int rr = idx >> 4, cl = idx & 15;
      int gi = i0 - 2 + rr, gj = cl - 2;
      Xt[cc][rr][cl] = (gi >= 0 && gi < 37 && gj >= 0 && gj < 12)
                           ? Xf[c * 444 + gi * 12 + gj] : 0.f;
    }
    for (int idx = tid; idx < 18 * 16; idx += 128) {
      int rr = idx >> 4, cl = idx & 15;
      int gi = i0 - 4 + rr, gj = cl - 2;
      Yt[cc][rr][cl] = (gi >= 0 && gi < 37 && gj >= 0 && gj < 12)
                           ? Yf[c * 444 + gi * 12 + gj] : 0.f;
    }
    for (int idx = tid; idx < 120; idx += 128) {
      int rr = idx / 12, gj = idx % 12;
      int gi = i0 + rr;
      bool ok = gi < 37;
      mX[cc][rr][gj] = ok ? muX_g[c * 444 + gi * 12 + gj] : 0.f;
      iX[cc][rr][gj] = ok ? ivX_g[c * 444 + gi * 12 + gj] : 0.f;
    }
    for (int idx = tid; idx < 168; idx += 128) {
      int rr = idx / 12, gj = idx % 12;
      int gi = i0 - 2 + rr;
      bool ok = (gi >= 0 && gi < 37);
      mY[cc][rr][gj] = ok ? muY_g[c * 444 + gi * 12 + gj] : 0.f;
      iY[cc][rr][gj] = ok ? ivY_g[c * 444 + gi * 12 + gj] : 0.f;
    }
  }
  __syncthreads();

  float acc[25];
#pragma unroll
  for (int o = 0; o < 25; ++o) acc[o] = 0.f;

  if (active) {
    for (int cc = 0; cc < 5; ++cc) {
      int c = cz * 5 + cc;
      float xp[5][5];
#pragma unroll
      for (int u = 0; u < 5; ++u)
#pragma unroll
        for (int v = 0; v < 5; ++v) xp[u][v] = Xt[cc][r + u][j + v];
      float muXv = mX[cc][r][j], ivXv = iX[cc][r][j];
      const float* wb = wr1t + c * 60 * 25;
      for (int d = 0; d < 5; ++d) {
        int yi = i0 + r + d - 2;
        if (yi < 0 || yi >= 37) continue;
        float win[5][5];
#pragma unroll
        for (int u = 0; u < 5; ++u)
#pragma unroll
          for (int v = 0; v < 5; ++v) win[u][v] = Yt[cc][r + d + u][v];
        for (int k = 0; k < 12; ++k) {
          if (k > 0) {
#pragma unroll
            for (int u = 0; u < 5; ++u) {
#pragma unroll
              for (int v = 0; v < 4; ++v) win[u][v] = win[u][v + 1];
              win[u][4] = Yt[cc][r + d + u][k + 4];
            }
          }
          float dot = 0.f;
#pragma unroll
          for (int u = 0; u < 5; ++u)
#pragma unroll
            for (int v = 0; v < 5; ++v) dot += xp[u][v] * win[u][v];
          float muYv = mY[cc][r + d][k], ivYv = iY[cc][r + d][k];
          float ncc = (dot - 25.f * muXv * muYv) * ivXv * ivYv * 0.04f;
          float rv = fmaxf(ncc, 0.f);
          const float* wo = wb + (d * 12 + k) * 25;
#pragma unroll
          for (int o = 0; o < 25; ++o) acc[o] += wo[o] * rv;
        }
      }
    }
  }

  if (active) {
    int i = i0 + r;
    float* p = part + ((long)(b * 5 + cz) * 25) * 444 + i * 12 + j;
#pragma unroll
    for (int o = 0; o < 25; ++o) p[o * 444] = acc[o];
  }
}

// ---------------- sum partials + bias + relu -> red1out ----------------
__global__ __launch_bounds__(256) void k_red1sum(
    const float* __restrict__ part, const float* __restrict__ b1,
    float* __restrict__ red1) {
  int b = blockIdx.x;
  for (int item = threadIdx.x; item < 25 * 444; item += 256) {
    int o = item / 444, px = item % 444;
    float s = b1[o];
#pragma unroll
    for (int cz = 0; cz < 5; ++cz)
      s += part[((long)(b * 5 + cz) * 25 + o) * 444 + px];
    red1[((long)b * 25 + o) * 444 + px] = fmaxf(s, 0.f);
  }
}

// ---------------- red2 3x3 conv + pool ----------------
__global__ __launch_bounds__(256) void k_red2(
    const float* __restrict__ red1, const float* __restrict__ w,
    const float* __restrict__ bias, float* __restrict__ r2p) {
  int b = blockIdx.x;
  __shared__ float inb[25 * 444];
  __shared__ float wl[25 * 25 * 9];
  for (int idx = threadIdx.x; idx < 25 * 444; idx += 256)
    inb[idx] = red1[(long)b * 25 * 444 + idx];
  for (int idx = threadIdx.x; idx < 25 * 25 * 9; idx += 256)
    wl[idx] = w[idx];
  __syncthreads();
  for (int item = threadIdx.x; item < 25 * 85; item += 256) {
    int oc = item / 85, rem = item % 85;
    int pi = rem / 5, pj = rem % 5;
    int ci0 = 2 * pi, cj0 = 2 * pj;
    float a00 = 0, a01 = 0, a10 = 0, a11 = 0;
    for (int ic = 0; ic < 25; ++ic) {
      const float* xp = inb + ic * 444 + ci0 * 12 + cj0;
      float win[4][4];
#pragma unroll
      for (int u = 0; u < 4; ++u)
#pragma unroll
        for (int v = 0; v < 4; ++v) win[u][v] = xp[u * 12 + v];
      const float* wq = wl + (oc * 25 + ic) * 9;
#pragma unroll
      for (int u = 0; u < 3; ++u)
#pragma unroll
        for (int v = 0; v < 3; ++v) {
          float wv = wq[u * 3 + v];
          a00 += wv * win[u][v];
          a01 += wv * win[u][v + 1];
          a10 += wv * win[u + 1][v];
          a11 += wv * win[u + 1][v + 1];
        }
    }
    float mx = fmaxf(fmaxf(a00, a01), fmaxf(a10, a11));
    r2p[(long)b * 2125 + item] = mx + bias[oc];   // no relu after red2
  }
}

// ---------------- lin1 GEMM partials: C[64][500] = X[64][2125] * Wlt ----------------
// grid (8 N-tiles, 17 K-chunks of 125); block 256; 4x4 outputs/thread.
__global__ __launch_bounds__(256) void k_lin1p(
    const float* __restrict__ r2p, const float* __restrict__ wlt,
    float* __restrict__ part) {
  int nb = blockIdx.x;           // o-tile: o0 = nb*64
  int kc = blockIdx.y;           // t-chunk: t0 = kc*125
  int o0 = nb * 64, t0 = kc * 125;
  int tid = threadIdx.x;
  __shared__ float Xs[64][126];  // +2 pad: compute-phase reads hit 16 distinct banks
  __shared__ float Ws[125][64];
  for (int idx = tid; idx < 64 * 125; idx += 256) {
    int b = idx / 125, tt = idx % 125;
    Xs[b][tt] = r2p[(long)b * 2125 + t0 + tt];
  }
  for (int idx = tid; idx < 125 * 64; idx += 256) {
    int tt = idx / 64, oo = idx % 64;
    int o = o0 + oo;
    Ws[tt][oo] = (o < 500) ? wlt[(long)(t0 + tt) * 500 + o] : 0.f;
  }
  __syncthreads();
  int b0 = (tid >> 4) << 2;      // 0,4,...,60
  int ol = (tid & 15) << 2;      // 0,4,...,60
  float acc[4][4];
#pragma unroll
  for (int i = 0; i < 4; ++i)
#pragma unroll
    for (int q = 0; q < 4; ++q) acc[i][q] = 0.f;
  for (int tt = 0; tt < 125; ++tt) {
    float xv[4];
#pragma unroll
    for (int i = 0; i < 4; ++i) xv[i] = Xs[b0 + i][tt];
    float4 wv = *reinterpret_cast<const float4*>(&Ws[tt][ol]);
#pragma unroll
    for (int i = 0; i < 4; ++i) {
      acc[i][0] += xv[i] * wv.x;
      acc[i][1] += xv[i] * wv.y;
      acc[i][2] += xv[i] * wv.z;
      acc[i][3] += xv[i] * wv.w;
    }
  }
#pragma unroll
  for (int i = 0; i < 4; ++i)
#pragma unroll
    for (int q = 0; q < 4; ++q)
      part[((long)kc * 64 + (b0 + i)) * 512 + o0 + ol + q] = acc[i][q];
}

// ---------------- lin1 reduce + bias, then lin2 fused ----------------
__global__ __launch_bounds__(512) void k_lin2(
    const float* __restrict__ part, const float* __restrict__ bl1,
    const float* __restrict__ wl2, const float* __restrict__ bl2,
    float* __restrict__ out) {
  int b = blockIdx.x;
  int o = threadIdx.x;
  float s = 0.f;
  if (o < 500) {
#pragma unroll
    for (int kc = 0; kc < 17; ++kc) s += part[((long)kc * 64 + b) * 512 + o];
    s += bl1[o];
  }
  __shared__ float red0[512], red1s[512];
  red0[o]  = (o < 500) ? s * wl2[o] : 0.f;
  red1s[o] = (o < 500) ? s * wl2[500 + o] : 0.f;
  __syncthreads();
  for (int st = 256; st >= 1; st >>= 1) {
    if (o < st) { red0[o] += red0[o + st]; red1s[o] += red1s[o + st]; }
    __syncthreads();
  }
  if (o == 0) {
    out[b * 2 + 0] = red0[0] + bl2[0];
    out[b * 2 + 1] = red1s[0] + bl2[1];
  }
}

// ---------------- launch ----------------
extern "C" void kernel_launch(void* const* d_in, const int* in_sizes, int n_in,
                              void* d_out, int out_size, void* d_ws, size_t ws_size,
                              hipStream_t stream) {
  const float* x1   = (const float*)d_in[0];
  const float* x2   = (const float*)d_in[1];
  const float* w1   = (const float*)d_in[2];
  const float* b1   = (const float*)d_in[3];
  const float* w2   = (const float*)d_in[4];
  const float* b2   = (const float*)d_in[5];
  const float* wr1  = (const float*)d_in[6];
  const float* br1  = (const float*)d_in[7];
  const float* wr2  = (const float*)d_in[8];
  const float* br2  = (const float*)d_in[9];
  const float* wl1  = (const float*)d_in[10];
  const float* bl1  = (const float*)d_in[11];
  const float* wl2  = (const float*)d_in[12];
  const float* bl2  = (const float*)d_in[13];
  float* out = (float*)d_out;
  float* ws  = (float*)d_ws;

  float* c1    = ws + OFF_C1;
  float* f     = ws + OFF_F;
  float* mu    = ws + OFF_MU;
  float* iv    = ws + OFF_IV;
  float* wlt   = ws + OFF_WLT;
  float* part  = ws + OFF_PART;
  float* red1  = ws + OFF_RED1;
  float* r2p   = ws + OFF_R2P;
  float* wr1t  = ws + OFF_WR1T;
  float* linp  = ws + OFF_LINP;

  hipLaunchKernelGGL(k_wt, dim3((2125 * 500 + 255) / 256), dim3(256), 0, stream, wl1, wlt);

  hipLaunchKernelGGL((k_conv1t<0, 7>),  dim3(128, 6), dim3(128), 0, stream, x1, x2, w1, b1, c1);
  hipLaunchKernelGGL((k_conv1t<7, 7>),  dim3(128, 6), dim3(128), 0, stream, x1, x2, w1, b1, c1);
  hipLaunchKernelGGL((k_conv1t<14, 6>), dim3(128, 6), dim3(128), 0, stream, x1, x2, w1, b1, c1);

  hipLaunchKernelGGL((k_conv2t<0, 7>),  dim3(128, 4), dim3(128), 0, stream, c1, w2, b2, f);
  hipLaunchKernelGGL((k_conv2t<7, 6>),  dim3(128, 4), dim3(128), 0, stream, c1, w2, b2, f);
  hipLaunchKernelGGL((k_conv2t<13, 6>), dim3(128, 4), dim3(128), 0, stream, c1, w2, b2, f);
  hipLaunchKernelGGL((k_conv2t<19, 6>), dim3(128, 4), dim3(128), 0, stream, c1, w2, b2, f);

  // wr1t lives in the (now dead) c1 region -> must launch after conv2
  hipLaunchKernelGGL(k_wrt, dim3(147), dim3(256), 0, stream, wr1, wr1t);

  hipLaunchKernelGGL(k_stats, dim3(128, 25), dim3(448), 0, stream, f, mu, iv);
  hipLaunchKernelGGL(k_ncc, dim3(64, 4, 5), dim3(128), 0, stream, f, mu, iv, wr1t, part);
  hipLaunchKernelGGL(k_red1sum, dim3(64), dim3(256), 0, stream, part, br1, red1);
  hipLaunchKernelGGL(k_red2, dim3(64), dim3(256), 0, stream, red1, wr2, br2, r2p);

  hipLaunchKernelGGL(k_lin1p, dim3(8, 17), dim3(256), 0, stream, r2p, wlt, linp);
  hipLaunchKernelGGL(k_lin2, dim3(64), dim3(512), 0, stream, linp, bl1, wl2, bl2, out);
}

// Round 6
// 351.861 us; speedup vs baseline: 2.2446x; 1.3395x over previous
//
#include <hip/hip_runtime.h>
#include <math.h>

// ---------------- geometry ----------------
// x: [img][3][160][60], img 0..127 (0..63 = x1, 64..127 = x2)
// conv1 5x5 VALID -> [20][156][56], relu, pool2 -> [20][78][28]
// conv2 5x5 VALID -> [25][74][24], relu, pool2 -> f [25][37][12]
// stats: mu, inv = 1/(std+0.01) per (img,c,i,j) over zero-padded 5x5 patch
// ncc = (dot - 25 muX muY) * invX * invY / 25 ; relu; 1x1 conv w_red1 -> [64][25][37][12]
// red2 3x3 VALID -> [35][10], pool2 -> [17][5]; flatten 2125; lin1 2125->500; lin2 500->2

// ws offsets in floats
static const long OFF_C1   = 0;          // [128][20][78][28] = 5,591,040
static const long OFF_F    = 5591040;    // [128][25][444]    = 1,420,800
static const long OFF_MU   = 7011840;    // [128][25][444]
static const long OFF_IV   = 8432640;    // [128][25][444]
static const long OFF_WLT  = 9853440;    // [2125][500]       = 1,062,500
// overlays of the dead-c1 region (valid after conv2 completes):
static const long OFF_PART = 0;          // ncc partials [64][5][25][444] = 3,552,000
static const long OFF_RED1 = 3552000;    // [64][25][444] = 710,400
static const long OFF_R2P  = 4262400;    // [64][2125]    = 136,000 (ends 4,398,400)
static const long OFF_WR1T = 4500000;    // [1500][25] = 37,500 (written after conv2)
static const long OFF_LINP = 0;          // lin1 partials [17][64][512] = 557,056 (after red2)

// ---------------- w_lin1 transpose: wlt[t][o] = wl1[o][t] ----------------
__global__ void k_wt(const float* __restrict__ wl1, float* __restrict__ wlt) {
  long idx = (long)blockIdx.x * 256 + threadIdx.x;
  if (idx < 2125L * 500) {
    long t = idx / 500, o = idx % 500;
    wlt[idx] = wl1[o * 2125 + t];
  }
}

// ---------------- w_red1 transpose: wr1t[(c*60+d*12+k)*25+o] ----------------
__global__ void k_wrt(const float* __restrict__ wr1, float* __restrict__ wr1t) {
  int idx = blockIdx.x * 256 + threadIdx.x;
  if (idx < 37500) {
    int o = idx / 1500, t = idx % 1500;
    wr1t[t * 25 + o] = wr1[idx];
  }
}

// ---------------- conv1 + relu + pool (merged oc-groups, NOC=5) ----------------
__global__ __launch_bounds__(128) void k_conv1(
    const float* __restrict__ x1, const float* __restrict__ x2,
    const float* __restrict__ w, const float* __restrict__ bias,
    float* __restrict__ out) {
  int img = blockIdx.x;
  int g   = blockIdx.y;          // 0..5, 13 pooled rows each (78 = 6*13)
  int oc0 = blockIdx.z * 5;      // 0,5,10,15
  int p0  = g * 13;
  const float* x = (img < 64) ? (x1 + (long)img * 28800)
                              : (x2 + (long)(img - 64) * 28800);
  for (int item = threadIdx.x; item < 13 * 28; item += 128) {
    int r = item / 28, j = item % 28;
    int ci0 = 2 * (p0 + r), cj0 = 2 * j;
    float acc[5][4];
#pragma unroll
    for (int o = 0; o < 5; ++o) {
      acc[o][0] = 0.f; acc[o][1] = 0.f; acc[o][2] = 0.f; acc[o][3] = 0.f;
    }
    for (int ic = 0; ic < 3; ++ic) {
      const float* xp = x + (long)ic * 9600 + ci0 * 60 + cj0;
      float win[6][6];
#pragma unroll
      for (int u = 0; u < 6; ++u)
#pragma unroll
        for (int v = 0; v < 6; ++v) win[u][v] = xp[u * 60 + v];
#pragma unroll
      for (int o = 0; o < 5; ++o) {
        const float* wq = w + ((oc0 + o) * 3 + ic) * 25;
#pragma unroll
        for (int u = 0; u < 5; ++u)
#pragma unroll
          for (int v = 0; v < 5; ++v) {
            float wv = wq[u * 5 + v];
            acc[o][0] += wv * win[u][v];
            acc[o][1] += wv * win[u][v + 1];
            acc[o][2] += wv * win[u + 1][v];
            acc[o][3] += wv * win[u + 1][v + 1];
          }
      }
    }
#pragma unroll
    for (int o = 0; o < 5; ++o) {
      float mx = fmaxf(fmaxf(acc[o][0], acc[o][1]), fmaxf(acc[o][2], acc[o][3]));
      out[((long)img * 20 + oc0 + o) * 2184 + (p0 + r) * 28 + j] =
          fmaxf(mx + bias[oc0 + o], 0.f);
    }
  }
}

// ---------------- conv2 + relu + pool (merged oc-groups, NOC=5) ----------------
__global__ __launch_bounds__(128) void k_conv2(
    const float* __restrict__ in, const float* __restrict__ w,
    const float* __restrict__ bias, float* __restrict__ out) {
  int img = blockIdx.x;
  int g   = blockIdx.y;          // 0..3 -> pooled rows p0..p0+9 (last: 7)
  int oc0 = blockIdx.z * 5;      // 0,5,10,15,20
  int p0  = g * 10;
  int ROWS = min(10, 37 - p0);
  int tid = threadIdx.x;
  int r = tid / 12, j = tid % 12;
  if (tid >= 120 || r >= ROWS) return;
  const float* x = in + (long)img * 20 * 2184;
  int ci0 = 2 * (p0 + r), cj0 = 2 * j;
  float acc[5][4];
#pragma unroll
  for (int o = 0; o < 5; ++o) {
    acc[o][0] = 0.f; acc[o][1] = 0.f; acc[o][2] = 0.f; acc[o][3] = 0.f;
  }
  for (int ic = 0; ic < 20; ++ic) {
    const float* xp = x + (long)ic * 2184 + ci0 * 28 + cj0;
    float win[6][6];
#pragma unroll
    for (int u = 0; u < 6; ++u)
#pragma unroll
      for (int v = 0; v < 6; ++v) win[u][v] = xp[u * 28 + v];
#pragma unroll
    for (int o = 0; o < 5; ++o) {
      const float* wq = w + ((oc0 + o) * 20 + ic) * 25;
#pragma unroll
      for (int u = 0; u < 5; ++u)
#pragma unroll
        for (int v = 0; v < 5; ++v) {
          float wv = wq[u * 5 + v];
          acc[o][0] += wv * win[u][v];
          acc[o][1] += wv * win[u][v + 1];
          acc[o][2] += wv * win[u + 1][v];
          acc[o][3] += wv * win[u + 1][v + 1];
        }
    }
  }
#pragma unroll
  for (int o = 0; o < 5; ++o) {
    float mx = fmaxf(fmaxf(acc[o][0], acc[o][1]), fmaxf(acc[o][2], acc[o][3]));
    out[((long)img * 25 + oc0 + o) * 444 + (p0 + r) * 12 + j] =
        fmaxf(mx + bias[oc0 + o], 0.f);
  }
}

// ---------------- patch stats: mu, 1/(std+eps) ----------------
__global__ __launch_bounds__(448) void k_stats(
    const float* __restrict__ f, float* __restrict__ mu, float* __restrict__ iv) {
  int img = blockIdx.x, c = blockIdx.y;
  int t = threadIdx.x;
  if (t >= 444) return;
  int i = t / 12, j = t % 12;
  const float* fp = f + ((long)img * 25 + c) * 444;
  float s = 0.f, sq = 0.f;
#pragma unroll
  for (int u = 0; u < 5; ++u) {
    int gi = i + u - 2;
    if (gi < 0 || gi >= 37) continue;
#pragma unroll
    for (int v = 0; v < 5; ++v) {
      int gj = j + v - 2;
      if (gj < 0 || gj >= 12) continue;
      float vv = fp[gi * 12 + gj];
      s += vv;
      sq += vv * vv;
    }
  }
  float m = s * 0.04f;
  float var = sq * 0.04f - m * m;
  float sd = sqrtf(fmaxf(var, 0.f));
  long idx = ((long)img * 25 + c) * 444 + t;
  mu[idx] = m;
  iv[idx] = 1.f / (sd + 0.01f);
}

// ---------------- fused NCC + relu + red1 (partial over c-groups) ----------------
// All 5 channels staged; mY holds muY*ivY; k-loop fully unrolled (no shifts).
__global__ __launch_bounds__(128) void k_ncc(
    const float* __restrict__ f, const float* __restrict__ mu,
    const float* __restrict__ iv, const float* __restrict__ wr1t,
    float* __restrict__ part) {
  int b  = blockIdx.x;          // 0..63
  int g  = blockIdx.y;          // 0..3 -> rows i0..i0+ROWS-1
  int cz = blockIdx.z;          // 0..4 -> channels cz*5..cz*5+4
  int i0 = g * 10;
  int ROWS = min(10, 37 - i0);
  int tid = threadIdx.x;
  int j = tid % 12, r = tid / 12;
  bool active = (r < ROWS);

  __shared__ float Xt[5][14][16], Yt[5][18][16];
  __shared__ float mX[5][10][12], iX[5][10][12];
  __shared__ float mY[5][14][12], iY[5][14][12];   // mY = muY*ivY, iY = ivY

  const float* Xf = f + (long)b * 25 * 444;
  const float* Yf = f + (long)(64 + b) * 25 * 444;
  const float* muX_g = mu + (long)b * 25 * 444;
  const float* ivX_g = iv + (long)b * 25 * 444;
  const float* muY_g = mu + (long)(64 + b) * 25 * 444;
  const float* ivY_g = iv + (long)(64 + b) * 25 * 444;

  // ---- stage all 5 channels ----
#pragma unroll 1
  for (int cc = 0; cc < 5; ++cc) {
    int c = cz * 5 + cc;
    for (int idx = tid; idx < 14 * 16; idx += 128) {
      int rr = idx >> 4, cl = idx & 15;
      int gi = i0 - 2 + rr, gj = cl - 2;
      Xt[cc][rr][cl] = (gi >= 0 && gi < 37 && gj >= 0 && gj < 12)
                           ? Xf[c * 444 + gi * 12 + gj] : 0.f;
    }
    for (int idx = tid; idx < 18 * 16; idx += 128) {
      int rr = idx >> 4, cl = idx & 15;
      int gi = i0 - 4 + rr, gj = cl - 2;
      Yt[cc][rr][cl] = (gi >= 0 && gi < 37 && gj >= 0 && gj < 12)
                           ? Yf[c * 444 + gi * 12 + gj] : 0.f;
    }
    for (int idx = tid; idx < 120; idx += 128) {
      int rr = idx / 12, gj = idx % 12;
      int gi = i0 + rr;
      bool ok = gi < 37;
      mX[cc][rr][gj] = ok ? muX_g[c * 444 + gi * 12 + gj] : 0.f;
      iX[cc][rr][gj] = ok ? ivX_g[c * 444 + gi * 12 + gj] : 0.f;
    }
    for (int idx = tid; idx < 168; idx += 128) {
      int rr = idx / 12, gj = idx % 12;
      int gi = i0 - 2 + rr;
      bool ok = (gi >= 0 && gi < 37);
      float muv = ok ? muY_g[c * 444 + gi * 12 + gj] : 0.f;
      float ivv = ok ? ivY_g[c * 444 + gi * 12 + gj] : 0.f;
      mY[cc][rr][gj] = muv * ivv;
      iY[cc][rr][gj] = ivv;
    }
  }
  __syncthreads();

  float acc[25];
#pragma unroll
  for (int o = 0; o < 25; ++o) acc[o] = 0.f;

  if (active) {
#pragma unroll 1
    for (int cc = 0; cc < 5; ++cc) {
      int c = cz * 5 + cc;
      float xp[5][5];
#pragma unroll
      for (int u = 0; u < 5; ++u)
#pragma unroll
        for (int v = 0; v < 5; ++v) xp[u][v] = Xt[cc][r + u][j + v];
      float muXv = mX[cc][r][j], ivXv = iX[cc][r][j];
      float sX = ivXv * 0.04f;
      float tX = muXv * ivXv;
      const float* wb = wr1t + c * 1500;
#pragma unroll 1
      for (int d = 0; d < 5; ++d) {
        int yi = i0 + r + d - 2;
        if (yi < 0 || yi >= 37) continue;
        float win[5][5];
#pragma unroll
        for (int u = 0; u < 5; ++u)
#pragma unroll
          for (int v = 0; v < 5; ++v) win[u][v] = Yt[cc][r + d + u][v];
#pragma unroll
        for (int k = 0; k < 12; ++k) {
          if (k > 0) {
#pragma unroll
            for (int u = 0; u < 5; ++u) {
#pragma unroll
              for (int v = 0; v < 4; ++v) win[u][v] = win[u][v + 1];
              win[u][4] = Yt[cc][r + d + u][k + 4];
            }
          }
          float rd[5];
#pragma unroll
          for (int u = 0; u < 5; ++u) {
            rd[u] = xp[u][0] * win[u][0];
#pragma unroll
            for (int v = 1; v < 5; ++v) rd[u] = fmaf(xp[u][v], win[u][v], rd[u]);
          }
          float dot = ((rd[0] + rd[1]) + (rd[2] + rd[3])) + rd[4];
          float ivYv = iY[cc][r + d][k];
          float miYv = mY[cc][r + d][k];
          float rv = fmaxf(fmaf(-tX, miYv, dot * sX * ivYv), 0.f);
          const float* wo = wb + (d * 12 + k) * 25;
#pragma unroll
          for (int o = 0; o < 25; ++o) acc[o] = fmaf(wo[o], rv, acc[o]);
        }
      }
    }
  }

  if (active) {
    int i = i0 + r;
    float* p = part + ((long)(b * 5 + cz) * 25) * 444 + i * 12 + j;
#pragma unroll
    for (int o = 0; o < 25; ++o) p[o * 444] = acc[o];
  }
}

// ---------------- sum partials + bias + relu -> red1out ----------------
__global__ __launch_bounds__(256) void k_red1sum(
    const float* __restrict__ part, const float* __restrict__ b1,
    float* __restrict__ red1) {
  int b = blockIdx.x;
  for (int item = threadIdx.x; item < 25 * 444; item += 256) {
    int o = item / 444, px = item % 444;
    float s = b1[o];
#pragma unroll
    for (int cz = 0; cz < 5; ++cz)
      s += part[((long)(b * 5 + cz) * 25 + o) * 444 + px];
    red1[((long)b * 25 + o) * 444 + px] = fmaxf(s, 0.f);
  }
}

// ---------------- red2 3x3 conv + pool ----------------
__global__ __launch_bounds__(256) void k_red2(
    const float* __restrict__ red1, const float* __restrict__ w,
    const float* __restrict__ bias, float* __restrict__ r2p) {
  int b = blockIdx.x;
  __shared__ float inb[25 * 444];
  __shared__ float wl[25 * 25 * 9];
  for (int idx = threadIdx.x; idx < 25 * 444; idx += 256)
    inb[idx] = red1[(long)b * 25 * 444 + idx];
  for (int idx = threadIdx.x; idx < 25 * 25 * 9; idx += 256)
    wl[idx] = w[idx];
  __syncthreads();
  for (int item = threadIdx.x; item < 25 * 85; item += 256) {
    int oc = item / 85, rem = item % 85;
    int pi = rem / 5, pj = rem % 5;
    int ci0 = 2 * pi, cj0 = 2 * pj;
    float a00 = 0, a01 = 0, a10 = 0, a11 = 0;
    for (int ic = 0; ic < 25; ++ic) {
      const float* xp = inb + ic * 444 + ci0 * 12 + cj0;
      float win[4][4];
#pragma unroll
      for (int u = 0; u < 4; ++u)
#pragma unroll
        for (int v = 0; v < 4; ++v) win[u][v] = xp[u * 12 + v];
      const float* wq = wl + (oc * 25 + ic) * 9;
#pragma unroll
      for (int u = 0; u < 3; ++u)
#pragma unroll
        for (int v = 0; v < 3; ++v) {
          float wv = wq[u * 3 + v];
          a00 += wv * win[u][v];
          a01 += wv * win[u][v + 1];
          a10 += wv * win[u + 1][v];
          a11 += wv * win[u + 1][v + 1];
        }
    }
    float mx = fmaxf(fmaxf(a00, a01), fmaxf(a10, a11));
    r2p[(long)b * 2125 + item] = mx + bias[oc];   // no relu after red2
  }
}

// ---------------- lin1 GEMM partials: C[64][500] = X[64][2125] * Wlt ----------------
__global__ __launch_bounds__(256) void k_lin1p(
    const float* __restrict__ r2p, const float* __restrict__ wlt,
    float* __restrict__ part) {
  int nb = blockIdx.x;           // o-tile: o0 = nb*64
  int kc = blockIdx.y;           // t-chunk: t0 = kc*125
  int o0 = nb * 64, t0 = kc * 125;
  int tid = threadIdx.x;
  __shared__ float Xs[64][126];
  __shared__ float Ws[125][64];
  for (int idx = tid; idx < 64 * 125; idx += 256) {
    int b = idx / 125, tt = idx % 125;
    Xs[b][tt] = r2p[(long)b * 2125 + t0 + tt];
  }
  for (int idx = tid; idx < 125 * 64; idx += 256) {
    int tt = idx / 64, oo = idx % 64;
    int o = o0 + oo;
    Ws[tt][oo] = (o < 500) ? wlt[(long)(t0 + tt) * 500 + o] : 0.f;
  }
  __syncthreads();
  int b0 = (tid >> 4) << 2;
  int ol = (tid & 15) << 2;
  float acc[4][4];
#pragma unroll
  for (int i = 0; i < 4; ++i)
#pragma unroll
    for (int q = 0; q < 4; ++q) acc[i][q] = 0.f;
  for (int tt = 0; tt < 125; ++tt) {
    float xv[4];
#pragma unroll
    for (int i = 0; i < 4; ++i) xv[i] = Xs[b0 + i][tt];
    float4 wv = *reinterpret_cast<const float4*>(&Ws[tt][ol]);
#pragma unroll
    for (int i = 0; i < 4; ++i) {
      acc[i][0] += xv[i] * wv.x;
      acc[i][1] += xv[i] * wv.y;
      acc[i][2] += xv[i] * wv.z;
      acc[i][3] += xv[i] * wv.w;
    }
  }
#pragma unroll
  for (int i = 0; i < 4; ++i)
#pragma unroll
    for (int q = 0; q < 4; ++q)
      part[((long)kc * 64 + (b0 + i)) * 512 + o0 + ol + q] = acc[i][q];
}

// ---------------- lin1 reduce + bias, then lin2 fused ----------------
__global__ __launch_bounds__(512) void k_lin2(
    const float* __restrict__ part, const float* __restrict__ bl1,
    const float* __restrict__ wl2, const float* __restrict__ bl2,
    float* __restrict__ out) {
  int b = blockIdx.x;
  int o = threadIdx.x;
  float s = 0.f;
  if (o < 500) {
#pragma unroll
    for (int kc = 0; kc < 17; ++kc) s += part[((long)kc * 64 + b) * 512 + o];
    s += bl1[o];
  }
  __shared__ float red0[512], red1s[512];
  red0[o]  = (o < 500) ? s * wl2[o] : 0.f;
  red1s[o] = (o < 500) ? s * wl2[500 + o] : 0.f;
  __syncthreads();
  for (int st = 256; st >= 1; st >>= 1) {
    if (o < st) { red0[o] += red0[o + st]; red1s[o] += red1s[o + st]; }
    __syncthreads();
  }
  if (o == 0) {
    out[b * 2 + 0] = red0[0] + bl2[0];
    out[b * 2 + 1] = red1s[0] + bl2[1];
  }
}

// ---------------- launch ----------------
extern "C" void kernel_launch(void* const* d_in, const int* in_sizes, int n_in,
                              void* d_out, int out_size, void* d_ws, size_t ws_size,
                              hipStream_t stream) {
  const float* x1   = (const float*)d_in[0];
  const float* x2   = (const float*)d_in[1];
  const float* w1   = (const float*)d_in[2];
  const float* b1   = (const float*)d_in[3];
  const float* w2   = (const float*)d_in[4];
  const float* b2   = (const float*)d_in[5];
  const float* wr1  = (const float*)d_in[6];
  const float* br1  = (const float*)d_in[7];
  const float* wr2  = (const float*)d_in[8];
  const float* br2  = (const float*)d_in[9];
  const float* wl1  = (const float*)d_in[10];
  const float* bl1  = (const float*)d_in[11];
  const float* wl2  = (const float*)d_in[12];
  const float* bl2  = (const float*)d_in[13];
  float* out = (float*)d_out;
  float* ws  = (float*)d_ws;

  float* c1    = ws + OFF_C1;
  float* f     = ws + OFF_F;
  float* mu    = ws + OFF_MU;
  float* iv    = ws + OFF_IV;
  float* wlt   = ws + OFF_WLT;
  float* part  = ws + OFF_PART;
  float* red1  = ws + OFF_RED1;
  float* r2p   = ws + OFF_R2P;
  float* wr1t  = ws + OFF_WR1T;
  float* linp  = ws + OFF_LINP;

  hipLaunchKernelGGL(k_wt, dim3((2125 * 500 + 255) / 256), dim3(256), 0, stream, wl1, wlt);

  hipLaunchKernelGGL(k_conv1, dim3(128, 6, 4), dim3(128), 0, stream, x1, x2, w1, b1, c1);
  hipLaunchKernelGGL(k_conv2, dim3(128, 4, 5), dim3(128), 0, stream, c1, w2, b2, f);

  // wr1t lives in the (now dead) c1 region -> must launch after conv2
  hipLaunchKernelGGL(k_wrt, dim3(147), dim3(256), 0, stream, wr1, wr1t);

  hipLaunchKernelGGL(k_stats, dim3(128, 25), dim3(448), 0, stream, f, mu, iv);
  hipLaunchKernelGGL(k_ncc, dim3(64, 4, 5), dim3(128), 0, stream, f, mu, iv, wr1t, part);
  hipLaunchKernelGGL(k_red1sum, dim3(64), dim3(256), 0, stream, part, br1, red1);
  hipLaunchKernelGGL(k_red2, dim3(64), dim3(256), 0, stream, red1, wr2, br2, r2p);

  hipLaunchKernelGGL(k_lin1p, dim3(8, 17), dim3(256), 0, stream, r2p, wlt, linp);
  hipLaunchKernelGGL(k_lin2, dim3(64), dim3(512), 0, stream, linp, bl1, wl2, bl2, out);
}